// Round 4
// baseline (317.253 us; speedup 1.0000x reference)
//
#include <hip/hip_runtime.h>
#include <hip/hip_bf16.h>
#include <stdint.h>

#define HN 16      // heads
#define TT 2048    // seq len (T == S)
#define BBATCH 2
#define EE 1024
#define HD 64
#define MM 4096    // TT*BBATCH

typedef __attribute__((ext_vector_type(8))) __bf16 bfrag;
typedef __attribute__((ext_vector_type(4))) float f32x4;

__device__ __forceinline__ void gll16(const void* g, void* lds) {
  __builtin_amdgcn_global_load_lds(
      (const __attribute__((address_space(1))) void*)g,
      (__attribute__((address_space(3))) void*)lds, 16, 0, 0);
}

__device__ __forceinline__ f32x4 mfma_bf16(bfrag a, bfrag b, f32x4 c) {
  return __builtin_amdgcn_mfma_f32_16x16x32_bf16(a, b, c, 0, 0, 0);
}

// ---- XOR-swizzled 64-elem-row LDS tiles (16B chunk c of row r at c^(r&7)) --
__device__ __forceinline__ const bfrag* fragp(const __bf16* base, int row, int e) {
  return (const bfrag*)(base + row * 64 + ((((e >> 3) ^ row) & 7) << 3));
}
__device__ __forceinline__ void stage8(const __bf16* grow0, int gstride,
                                       __bf16* tile, int r0, int lane) {
  const int rr = lane >> 3;
  const int cl = (lane & 7) ^ rr;
  gll16(grow0 + (size_t)(r0 + rr) * gstride + cl * 8, tile + r0 * 64);
}

// ---------------- fp32 -> bf16 conversion (7 tensors in one launch) -------
struct CvtArgs {
  const float* src[7];
  __bf16* dst[7];
  int n4[7];
};

__global__ __launch_bounds__(256) void cvt_all(CvtArgs a) {
  const int z = blockIdx.z;
  const int i = blockIdx.x * 256 + threadIdx.x;
  if (i < a.n4[z]) {
    float4 v = ((const float4*)a.src[z])[i];
    struct alignas(8) B4 { __bf16 a0, a1, a2, a3; };
    B4 o = {(__bf16)v.x, (__bf16)v.y, (__bf16)v.z, (__bf16)v.w};
    ((B4*)a.dst[z])[i] = o;
  }
}

// ---------------- GEMM: C(MMxEE) = X(MMxEE) * W(EExEE)^T + bias ----------
__device__ __forceinline__ void gemm_core(const __bf16* __restrict__ X,
                                          const __bf16* __restrict__ W,
                                          const float* __restrict__ bias,
                                          void* __restrict__ out, int mode) {
  __shared__ __bf16 As[128 * 32];
  __shared__ __bf16 Bs[128 * 32];
  const int tid = threadIdx.x;
  const int lane = tid & 63, wave = tid >> 6;
  const int wm = wave >> 1, wn = wave & 1;
  const int quad = lane >> 4, l16 = lane & 15;
  const int m0 = blockIdx.y * 128, n0 = blockIdx.x * 128;
  const int srow = lane >> 2;
  const int scol = (lane & 3) * 8;
  const int c0 = 2 * wave;

  f32x4 acc[4][4] = {};

  for (int k0 = 0; k0 < EE; k0 += 32) {
    #pragma unroll
    for (int c = 0; c < 2; ++c) {
      const int ch = c0 + c;
      gll16(X + (size_t)(m0 + ch * 16 + srow) * EE + k0 + scol, As + ch * 512);
      gll16(W + (size_t)(n0 + ch * 16 + srow) * EE + k0 + scol, Bs + ch * 512);
    }
    __syncthreads();
    bfrag a[4], b[4];
    #pragma unroll
    for (int f = 0; f < 4; ++f)
      a[f] = *(const bfrag*)(As + (wm * 64 + f * 16 + l16) * 32 + quad * 8);
    #pragma unroll
    for (int f = 0; f < 4; ++f)
      b[f] = *(const bfrag*)(Bs + (wn * 64 + f * 16 + l16) * 32 + quad * 8);
    #pragma unroll
    for (int fm = 0; fm < 4; ++fm)
      #pragma unroll
      for (int fn = 0; fn < 4; ++fn)
        acc[fm][fn] = mfma_bf16(a[fm], b[fn], acc[fm][fn]);
    __syncthreads();
  }

  float bv[4];
  #pragma unroll
  for (int fn = 0; fn < 4; ++fn) bv[fn] = bias[n0 + wn * 64 + fn * 16 + l16];

  #pragma unroll
  for (int fm = 0; fm < 4; ++fm) {
    #pragma unroll
    for (int r = 0; r < 4; ++r) {
      const int gm = m0 + wm * 64 + fm * 16 + quad * 4 + r;
      #pragma unroll
      for (int fn = 0; fn < 4; ++fn) {
        const int gn = n0 + wn * 64 + fn * 16 + l16;
        const float v = acc[fm][fn][r] + bv[fn];
        if (mode == 0) {
          const int t = gm >> 1, bb = gm & 1, h = gn >> 6, d = gn & 63;
          ((__bf16*)out)[(((size_t)(bb * HN + h)) * TT + t) * HD + d] = (__bf16)v;
        } else {
          const int s = gm >> 1, bb = gm & 1, h = gn >> 6, d = gn & 63;
          ((__bf16*)out)[(((size_t)(bb * HN + h)) * HD + d) * TT + s] = (__bf16)v;
        }
      }
    }
  }
}

__global__ __launch_bounds__(256) void gemm_qkv(
    const __bf16* __restrict__ xq, const __bf16* __restrict__ xk,
    const __bf16* __restrict__ xv, const __bf16* __restrict__ wq,
    const __bf16* __restrict__ wk, const __bf16* __restrict__ wv,
    const float* __restrict__ bq, const float* __restrict__ bk,
    const float* __restrict__ bv, __bf16* __restrict__ qo,
    __bf16* __restrict__ ko, __bf16* __restrict__ vo) {
  const __bf16 *X, *W;
  const float* bias;
  __bf16* out;
  int mode;
  if (blockIdx.z == 0)      { X = xq; W = wq; bias = bq; out = qo; mode = 0; }
  else if (blockIdx.z == 1) { X = xk; W = wk; bias = bk; out = ko; mode = 0; }
  else                      { X = xv; W = wv; bias = bv; out = vo; mode = 2; }
  gemm_core(X, W, bias, out, mode);
}

// ---- output GEMM: 64x128 tile for 512 blocks ----------------------------
__global__ __launch_bounds__(256) void gemm_o64(const __bf16* __restrict__ X,
                                                const __bf16* __restrict__ W,
                                                const float* __restrict__ bias,
                                                float* __restrict__ out) {
  __shared__ __bf16 As[64 * 32];
  __shared__ __bf16 Bs[128 * 32];
  const int tid = threadIdx.x;
  const int lane = tid & 63, wave = tid >> 6;
  const int quad = lane >> 4, l16 = lane & 15;
  const int m0 = blockIdx.y * 64, n0 = blockIdx.x * 128;
  const int srow = lane >> 2, scol = (lane & 3) * 8;

  f32x4 acc[4][2] = {};

  for (int k0 = 0; k0 < EE; k0 += 32) {
    gll16(X + (size_t)(m0 + wave * 16 + srow) * EE + k0 + scol, As + wave * 512);
    #pragma unroll
    for (int c = 0; c < 2; ++c) {
      const int ch = 2 * wave + c;
      gll16(W + (size_t)(n0 + ch * 16 + srow) * EE + k0 + scol, Bs + ch * 512);
    }
    __syncthreads();
    bfrag a[4], b2[2];
    #pragma unroll
    for (int f = 0; f < 4; ++f)
      a[f] = *(const bfrag*)(As + (f * 16 + l16) * 32 + quad * 8);
    #pragma unroll
    for (int f = 0; f < 2; ++f)
      b2[f] = *(const bfrag*)(Bs + (wave * 32 + f * 16 + l16) * 32 + quad * 8);
    #pragma unroll
    for (int fm = 0; fm < 4; ++fm)
      #pragma unroll
      for (int fn = 0; fn < 2; ++fn)
        acc[fm][fn] = mfma_bf16(a[fm], b2[fn], acc[fm][fn]);
    __syncthreads();
  }

  float bv[2];
  #pragma unroll
  for (int fn = 0; fn < 2; ++fn) bv[fn] = bias[n0 + wave * 32 + fn * 16 + l16];

  #pragma unroll
  for (int fm = 0; fm < 4; ++fm)
    #pragma unroll
    for (int r = 0; r < 4; ++r) {
      const int gm = m0 + fm * 16 + quad * 4 + r;
      #pragma unroll
      for (int fn = 0; fn < 2; ++fn) {
        const int gn = n0 + wave * 32 + fn * 16 + l16;
        out[(size_t)gm * EE + gn] = acc[fm][fn][r] + bv[fn];
      }
    }
}

// ---------------- flash attention fwd: O (normalized) + linv -------------
// 128 threads = 2 waves, each owning 64t x 64s. t-tile 128, grid (16,16,2).
// QK computed TRANSPOSED (S^T = K.Q via swapped mfma operands) so each lane
// holds 4 CONSECUTIVE s per t-row -> P packs into ds_write_b64 (16/iter vs
// 32 scalar b16) and row-sums reduce with 2 shuffles at loop end.
// LDS per wave-iter: 8 kf + 8 vf + 8 pf b128 + 16 b64 writes = 32KB for
// 64 MFMA (~500B/MFMA vs r3's 1500B/MFMA).
__global__ __launch_bounds__(128) void attn_fwd(const __bf16* __restrict__ qb,
                                                const __bf16* __restrict__ kb,
                                                const __bf16* __restrict__ vtb,
                                                __bf16* __restrict__ ob,
                                                float* __restrict__ linv_ws) {
  __shared__ __bf16 QP[128 * 64];      // Q tile, reused as P tile (16KB)
  __shared__ __bf16 Ks[2][64 * 64];    // 2 x 8KB
  __shared__ __bf16 Vs[2][64 * 64];    // 2 x 8KB  (V^T: [d][s])
  __shared__ float LinvS[128];

  const int tid = threadIdx.x, lane = tid & 63, w = tid >> 6;  // w in {0,1}
  const int quad = lane >> 4, l16 = lane & 15;
  const int t0 = blockIdx.x * 128;
  const int h = blockIdx.y, b = blockIdx.z;
  const size_t bh = (size_t)(b * HN + h);

  const __bf16* qbase = qb + (bh * TT + t0) * HD;
  const __bf16* kbase = kb + bh * TT * HD;
  const __bf16* vbase = vtb + bh * HD * TT;

  // stage Q (128 rows) + K/V for it=0 (64 rows each)
  #pragma unroll
  for (int c = 0; c < 8; ++c) stage8(qbase, HD, QP, w * 64 + c * 8, lane);
  #pragma unroll
  for (int c = 0; c < 4; ++c) {
    stage8(kbase, HD, Ks[0], w * 32 + c * 8, lane);
    stage8(vbase, TT, Vs[0], w * 32 + c * 8, lane);
  }
  __syncthreads();

  // Q frags (B-operand for swapped QK): rows w*64 + fn*16 + l16, loop-invariant
  bfrag qf[4][2];
  #pragma unroll
  for (int fn = 0; fn < 4; ++fn)
    #pragma unroll
    for (int ks = 0; ks < 2; ++ks)
      qf[fn][ks] = *fragp(QP, w * 64 + fn * 16 + l16, ks * 32 + quad * 8);

  f32x4 oacc[4][4] = {};   // [fm_t][fn_d]
  float lpart[4] = {};     // per fn_t (t = fn*16 + l16); quads hold disjoint s

  for (int it = 0; it < TT / 64; ++it) {
    const int cur = it & 1;
    if (it) __syncthreads();
    if (it + 1 < TT / 64) {
      const int s1 = (it + 1) * 64;
      #pragma unroll
      for (int c = 0; c < 4; ++c) {
        stage8(kbase + (size_t)s1 * HD, HD, Ks[1 - cur], w * 32 + c * 8, lane);
        stage8(vbase + s1, TT, Vs[1 - cur], w * 32 + c * 8, lane);
      }
    }

    // ---- S^T[s][t] = K.Q : A = K (m=s, 4 frags), B = Q (n=t, 4 frags)
    f32x4 sacc[4][4] = {};   // [fm_s][fn_t]
    #pragma unroll
    for (int ks = 0; ks < 2; ++ks) {
      bfrag kf[4];
      #pragma unroll
      for (int f = 0; f < 4; ++f)
        kf[f] = *fragp(Ks[cur], f * 16 + l16, ks * 32 + quad * 8);
      #pragma unroll
      for (int fm = 0; fm < 4; ++fm)
        #pragma unroll
        for (int fn = 0; fn < 4; ++fn)
          sacc[fm][fn] = mfma_bf16(kf[fm], qf[fn][ks], sacc[fm][fn]);
    }

    // ---- exp; lane holds P[t=fn*16+l16][s=fm*16+quad*4+r] -> 4 consecutive
    // s per (fm,fn): pack to one ds_write_b64 into swizzled P tile [t][s].
    #pragma unroll
    for (int fn = 0; fn < 4; ++fn) {
      const int row = w * 64 + fn * 16 + l16;
      float acc_l = 0.0f;
      #pragma unroll
      for (int fm = 0; fm < 4; ++fm) {
        float p0 = __expf(sacc[fm][fn][0] * 0.125f);
        float p1 = __expf(sacc[fm][fn][1] * 0.125f);
        float p2 = __expf(sacc[fm][fn][2] * 0.125f);
        float p3 = __expf(sacc[fm][fn][3] * 0.125f);
        acc_l += (p0 + p1) + (p2 + p3);
        struct alignas(8) B4 { __bf16 v0, v1, v2, v3; };
        B4 pk = {(__bf16)p0, (__bf16)p1, (__bf16)p2, (__bf16)p3};
        const int chunk = (fm * 2 + (quad >> 1)) ^ (row & 7);
        *(B4*)(QP + row * 64 + chunk * 8 + (quad & 1) * 4) = pk;
      }
      lpart[fn] += acc_l;
    }

    // ---- O[t][d] += P[t][s] . V^T : A = P (4 frags), B = V (4 frags)
    #pragma unroll
    for (int ks = 0; ks < 2; ++ks) {
      bfrag pf[4], vf[4];
      #pragma unroll
      for (int f = 0; f < 4; ++f)
        pf[f] = *fragp(QP, w * 64 + f * 16 + l16, ks * 32 + quad * 8);
      #pragma unroll
      for (int f = 0; f < 4; ++f)
        vf[f] = *fragp(Vs[cur], f * 16 + l16, ks * 32 + quad * 8);
      #pragma unroll
      for (int fm = 0; fm < 4; ++fm)
        #pragma unroll
        for (int fn = 0; fn < 4; ++fn)
          oacc[fm][fn] = mfma_bf16(pf[fm], vf[fn], oacc[fm][fn]);
    }
  }

  // ---- row sums: quads hold disjoint s -> butterfly over quad bits
  #pragma unroll
  for (int fn = 0; fn < 4; ++fn) {
    float v = lpart[fn];
    v += __shfl_xor(v, 16);
    v += __shfl_xor(v, 32);
    const float linv = 1.0f / v;
    if (quad == 0) {
      LinvS[w * 64 + fn * 16 + l16] = linv;
      linv_ws[bh * TT + t0 + w * 64 + fn * 16 + l16] = linv;
    }
  }
  // same-wave LDS write->read: no barrier needed
  #pragma unroll
  for (int fm = 0; fm < 4; ++fm) {
    const f32x4 lv = *(const f32x4*)&LinvS[w * 64 + fm * 16 + quad * 4];
    #pragma unroll
    for (int r = 0; r < 4; ++r) {
      const int row = w * 64 + fm * 16 + quad * 4 + r;
      #pragma unroll
      for (int fn = 0; fn < 4; ++fn) {
        const int d = fn * 16 + l16;
        ob[((size_t)(t0 + row) * BBATCH + b) * EE + h * HD + d] =
            (__bf16)(oacc[fm][fn][r] * lv[r]);
      }
    }
  }
}

// ---------------- avg_w: mean over heads of softmax probs ----------------
// 128 threads = 2 waves of 64t x 64s. Q+K double-buffered over h. linv read
// as f32x4 vector loads (L2-hot). grid (32 s-tiles, 16 t-tiles, 2).
__global__ __launch_bounds__(128) void avg_attn(const __bf16* __restrict__ qb,
                                                const __bf16* __restrict__ kb,
                                                const float* __restrict__ linv_ws,
                                                float* __restrict__ avg_out) {
  __shared__ __bf16 Qs[2][128 * 64];   // 2 x 16KB
  __shared__ __bf16 Ks2[2][64 * 64];   // 2 x 8KB

  const int tid = threadIdx.x, lane = tid & 63, w = tid >> 6;
  const int quad = lane >> 4, l16 = lane & 15;
  const int s0 = blockIdx.x * 64, t0 = blockIdx.y * 128;
  const int b = blockIdx.z;

  {
    const size_t bh0 = (size_t)b * HN;
    #pragma unroll
    for (int c = 0; c < 8; ++c)
      stage8(qb + (bh0 * TT + t0) * HD, HD, Qs[0], w * 64 + c * 8, lane);
    #pragma unroll
    for (int c = 0; c < 4; ++c)
      stage8(kb + (bh0 * TT + s0) * HD, HD, Ks2[0], w * 32 + c * 8, lane);
  }

  f32x4 aacc[4][4] = {};

  for (int h = 0; h < HN; ++h) {
    const int cur = h & 1;
    const size_t bh = (size_t)(b * HN + h);
    __syncthreads();
    if (h + 1 < HN) {
      const size_t bh1 = bh + 1;
      #pragma unroll
      for (int c = 0; c < 8; ++c)
        stage8(qb + (bh1 * TT + t0) * HD, HD, Qs[1 - cur], w * 64 + c * 8, lane);
      #pragma unroll
      for (int c = 0; c < 4; ++c)
        stage8(kb + (bh1 * TT + s0) * HD, HD, Ks2[1 - cur], w * 32 + c * 8, lane);
    }

    // S[t][s]: A = Q (m=t, 4 frags), B = K (n=s, 4 frags)
    f32x4 sacc[4][4] = {};
    #pragma unroll
    for (int ks = 0; ks < 2; ++ks) {
      bfrag qf4[4], kf4[4];
      #pragma unroll
      for (int f = 0; f < 4; ++f)
        qf4[f] = *fragp(Qs[cur], w * 64 + f * 16 + l16, ks * 32 + quad * 8);
      #pragma unroll
      for (int f = 0; f < 4; ++f)
        kf4[f] = *fragp(Ks2[cur], f * 16 + l16, ks * 32 + quad * 8);
      #pragma unroll
      for (int fm = 0; fm < 4; ++fm)
        #pragma unroll
        for (int fn = 0; fn < 4; ++fn)
          sacc[fm][fn] = mfma_bf16(qf4[fm], kf4[fn], sacc[fm][fn]);
    }

    f32x4 lvv[4];
    #pragma unroll
    for (int fm = 0; fm < 4; ++fm)
      lvv[fm] = *(const f32x4*)&linv_ws[bh * TT + t0 + w * 64 + fm * 16 + quad * 4];

    #pragma unroll
    for (int fm = 0; fm < 4; ++fm)
      #pragma unroll
      for (int fn = 0; fn < 4; ++fn)
        #pragma unroll
        for (int r = 0; r < 4; ++r)
          aacc[fm][fn][r] += __expf(sacc[fm][fn][r] * 0.125f) * lvv[fm][r];
  }

  const float invh = 1.0f / (float)HN;
  #pragma unroll
  for (int fm = 0; fm < 4; ++fm)
    #pragma unroll
    for (int r = 0; r < 4; ++r) {
      const int t = t0 + w * 64 + fm * 16 + quad * 4 + r;
      #pragma unroll
      for (int fn = 0; fn < 4; ++fn) {
        const int s = s0 + fn * 16 + l16;
        avg_out[((size_t)b * TT + t) * TT + s] = aacc[fm][fn][r] * invh;
      }
    }
}

extern "C" void kernel_launch(void* const* d_in, const int* in_sizes, int n_in,
                              void* d_out, int out_size, void* d_ws, size_t ws_size,
                              hipStream_t stream) {
  (void)in_sizes; (void)n_in; (void)out_size; (void)ws_size;
  const float* query = (const float*)d_in[0];
  const float* key   = (const float*)d_in[1];
  const float* value = (const float*)d_in[2];
  const float* Wq = (const float*)d_in[3];
  const float* bq = (const float*)d_in[4];
  const float* Wk = (const float*)d_in[5];
  const float* bk = (const float*)d_in[6];
  const float* Wv = (const float*)d_in[7];
  const float* bv = (const float*)d_in[8];
  const float* Wo = (const float*)d_in[9];
  const float* bo = (const float*)d_in[10];

  char* ws = (char*)d_ws;
  size_t off = 0;
  auto wsalloc = [&](size_t bytes) -> void* {
    void* p = ws + off;
    off += (bytes + 255) & ~(size_t)255;
    return p;
  };
  const size_t XE = (size_t)MM * EE;
  const size_t WE = (size_t)EE * EE;
  __bf16* xq   = (__bf16*)wsalloc(XE * 2);
  __bf16* xk   = (__bf16*)wsalloc(XE * 2);
  __bf16* xv   = (__bf16*)wsalloc(XE * 2);
  __bf16* wqb  = (__bf16*)wsalloc(WE * 2);
  __bf16* wkb  = (__bf16*)wsalloc(WE * 2);
  __bf16* wvb  = (__bf16*)wsalloc(WE * 2);
  __bf16* wob  = (__bf16*)wsalloc(WE * 2);
  __bf16* qbuf = (__bf16*)wsalloc(XE * 2);
  __bf16* kbuf = (__bf16*)wsalloc(XE * 2);
  __bf16* vtbuf= (__bf16*)wsalloc(XE * 2);
  __bf16* obuf = (__bf16*)wsalloc(XE * 2);
  float* linv  = (float*)wsalloc((size_t)BBATCH * HN * TT * 4);

  CvtArgs ca;
  ca.src[0] = query; ca.dst[0] = xq;  ca.n4[0] = (int)(XE / 4);
  ca.src[1] = key;   ca.dst[1] = xk;  ca.n4[1] = (int)(XE / 4);
  ca.src[2] = value; ca.dst[2] = xv;  ca.n4[2] = (int)(XE / 4);
  ca.src[3] = Wq;    ca.dst[3] = wqb; ca.n4[3] = (int)(WE / 4);
  ca.src[4] = Wk;    ca.dst[4] = wkb; ca.n4[4] = (int)(WE / 4);
  ca.src[5] = Wv;    ca.dst[5] = wvb; ca.n4[5] = (int)(WE / 4);
  ca.src[6] = Wo;    ca.dst[6] = wob; ca.n4[6] = (int)(WE / 4);
  cvt_all<<<dim3(4096, 1, 7), 256, 0, stream>>>(ca);

  gemm_qkv<<<dim3(8, 32, 3), 256, 0, stream>>>(xq, xk, xv, wqb, wkb, wvb,
                                               bq, bk, bv, qbuf, kbuf, vtbuf);

  attn_fwd<<<dim3(16, HN, BBATCH), 128, 0, stream>>>(qbuf, kbuf, vtbuf, obuf, linv);

  float* avg_out = (float*)d_out + (size_t)TT * BBATCH * EE;
  avg_attn<<<dim3(32, 16, 2), 128, 0, stream>>>(qbuf, kbuf, linv, avg_out);

  gemm_o64<<<dim3(8, 64), 256, 0, stream>>>(obuf, wob, bo, (float*)d_out);
}

// Round 5
// 313.786 us; speedup vs baseline: 1.0110x; 1.0110x over previous
//
#include <hip/hip_runtime.h>
#include <hip/hip_bf16.h>
#include <stdint.h>

#define HN 16      // heads
#define TT 2048    // seq len (T == S)
#define BBATCH 2
#define EE 1024
#define HD 64
#define MM 4096    // TT*BBATCH

typedef __attribute__((ext_vector_type(8))) __bf16 bfrag;
typedef __attribute__((ext_vector_type(4))) float f32x4;
typedef __attribute__((ext_vector_type(4))) short s16x4;

__device__ __forceinline__ void gll16(const void* g, void* lds) {
  __builtin_amdgcn_global_load_lds(
      (const __attribute__((address_space(1))) void*)g,
      (__attribute__((address_space(3))) void*)lds, 16, 0, 0);
}

__device__ __forceinline__ f32x4 mfma_bf16(bfrag a, bfrag b, f32x4 c) {
  return __builtin_amdgcn_mfma_f32_16x16x32_bf16(a, b, c, 0, 0, 0);
}

// ---- XOR-swizzled 64-elem-row LDS tiles (16B chunk c of row r at c^(r&7)) --
__device__ __forceinline__ const bfrag* fragp(const __bf16* base, int row, int e) {
  return (const bfrag*)(base + row * 64 + ((((e >> 3) ^ row) & 7) << 3));
}
__device__ __forceinline__ void stage8(const __bf16* grow0, int gstride,
                                       __bf16* tile, int r0, int lane) {
  const int rr = lane >> 3;
  const int cl = (lane & 7) ^ rr;
  gll16(grow0 + (size_t)(r0 + rr) * gstride + cl * 8, tile + r0 * 64);
}

// ---------------- fp32 -> bf16 conversion (7 tensors in one launch) -------
struct CvtArgs {
  const float* src[7];
  __bf16* dst[7];
  int n4[7];
};

__global__ __launch_bounds__(256) void cvt_all(CvtArgs a) {
  const int z = blockIdx.z;
  const int i = blockIdx.x * 256 + threadIdx.x;
  if (i < a.n4[z]) {
    float4 v = ((const float4*)a.src[z])[i];
    struct alignas(8) B4 { __bf16 a0, a1, a2, a3; };
    B4 o = {(__bf16)v.x, (__bf16)v.y, (__bf16)v.z, (__bf16)v.w};
    ((B4*)a.dst[z])[i] = o;
  }
}

// ---------------- GEMM: C(MMxEE) = X(MMxEE) * W(EExEE)^T + bias ----------
// scale folded into epilogue (Q gets 1/8 so attention skips the mul).
__device__ __forceinline__ void gemm_core(const __bf16* __restrict__ X,
                                          const __bf16* __restrict__ W,
                                          const float* __restrict__ bias,
                                          void* __restrict__ out, int mode,
                                          float scale) {
  __shared__ __bf16 As[128 * 32];
  __shared__ __bf16 Bs[128 * 32];
  const int tid = threadIdx.x;
  const int lane = tid & 63, wave = tid >> 6;
  const int wm = wave >> 1, wn = wave & 1;
  const int quad = lane >> 4, l16 = lane & 15;
  const int m0 = blockIdx.y * 128, n0 = blockIdx.x * 128;
  const int srow = lane >> 2;
  const int scol = (lane & 3) * 8;
  const int c0 = 2 * wave;

  f32x4 acc[4][4] = {};

  for (int k0 = 0; k0 < EE; k0 += 32) {
    #pragma unroll
    for (int c = 0; c < 2; ++c) {
      const int ch = c0 + c;
      gll16(X + (size_t)(m0 + ch * 16 + srow) * EE + k0 + scol, As + ch * 512);
      gll16(W + (size_t)(n0 + ch * 16 + srow) * EE + k0 + scol, Bs + ch * 512);
    }
    __syncthreads();
    bfrag a[4], b[4];
    #pragma unroll
    for (int f = 0; f < 4; ++f)
      a[f] = *(const bfrag*)(As + (wm * 64 + f * 16 + l16) * 32 + quad * 8);
    #pragma unroll
    for (int f = 0; f < 4; ++f)
      b[f] = *(const bfrag*)(Bs + (wn * 64 + f * 16 + l16) * 32 + quad * 8);
    #pragma unroll
    for (int fm = 0; fm < 4; ++fm)
      #pragma unroll
      for (int fn = 0; fn < 4; ++fn)
        acc[fm][fn] = mfma_bf16(a[fm], b[fn], acc[fm][fn]);
    __syncthreads();
  }

  float bv[4];
  #pragma unroll
  for (int fn = 0; fn < 4; ++fn) bv[fn] = bias[n0 + wn * 64 + fn * 16 + l16];

  #pragma unroll
  for (int fm = 0; fm < 4; ++fm) {
    #pragma unroll
    for (int r = 0; r < 4; ++r) {
      const int gm = m0 + wm * 64 + fm * 16 + quad * 4 + r;
      #pragma unroll
      for (int fn = 0; fn < 4; ++fn) {
        const int gn = n0 + wn * 64 + fn * 16 + l16;
        const float v = (acc[fm][fn][r] + bv[fn]) * scale;
        if (mode == 0) {
          const int t = gm >> 1, bb = gm & 1, h = gn >> 6, d = gn & 63;
          ((__bf16*)out)[(((size_t)(bb * HN + h)) * TT + t) * HD + d] = (__bf16)v;
        } else {
          const int s = gm >> 1, bb = gm & 1, h = gn >> 6, d = gn & 63;
          ((__bf16*)out)[(((size_t)(bb * HN + h)) * HD + d) * TT + s] = (__bf16)v;
        }
      }
    }
  }
}

__global__ __launch_bounds__(256) void gemm_qkv(
    const __bf16* __restrict__ xq, const __bf16* __restrict__ xk,
    const __bf16* __restrict__ xv, const __bf16* __restrict__ wq,
    const __bf16* __restrict__ wk, const __bf16* __restrict__ wv,
    const float* __restrict__ bq, const float* __restrict__ bk,
    const float* __restrict__ bv, __bf16* __restrict__ qo,
    __bf16* __restrict__ ko, __bf16* __restrict__ vo) {
  const __bf16 *X, *W;
  const float* bias;
  __bf16* out;
  int mode;
  float scale;
  if (blockIdx.z == 0)      { X = xq; W = wq; bias = bq; out = qo; mode = 0; scale = 0.125f; }
  else if (blockIdx.z == 1) { X = xk; W = wk; bias = bk; out = ko; mode = 0; scale = 1.0f; }
  else                      { X = xv; W = wv; bias = bv; out = vo; mode = 2; scale = 1.0f; }
  gemm_core(X, W, bias, out, mode, scale);
}

// ---- output GEMM: 64x128 tile for 512 blocks ----------------------------
__global__ __launch_bounds__(256) void gemm_o64(const __bf16* __restrict__ X,
                                                const __bf16* __restrict__ W,
                                                const float* __restrict__ bias,
                                                float* __restrict__ out) {
  __shared__ __bf16 As[64 * 32];
  __shared__ __bf16 Bs[128 * 32];
  const int tid = threadIdx.x;
  const int lane = tid & 63, wave = tid >> 6;
  const int quad = lane >> 4, l16 = lane & 15;
  const int m0 = blockIdx.y * 64, n0 = blockIdx.x * 128;
  const int srow = lane >> 2, scol = (lane & 3) * 8;

  f32x4 acc[4][2] = {};

  for (int k0 = 0; k0 < EE; k0 += 32) {
    gll16(X + (size_t)(m0 + wave * 16 + srow) * EE + k0 + scol, As + wave * 512);
    #pragma unroll
    for (int c = 0; c < 2; ++c) {
      const int ch = 2 * wave + c;
      gll16(W + (size_t)(n0 + ch * 16 + srow) * EE + k0 + scol, Bs + ch * 512);
    }
    __syncthreads();
    bfrag a[4], b2[2];
    #pragma unroll
    for (int f = 0; f < 4; ++f)
      a[f] = *(const bfrag*)(As + (f * 16 + l16) * 32 + quad * 8);
    #pragma unroll
    for (int f = 0; f < 2; ++f)
      b2[f] = *(const bfrag*)(Bs + (wave * 32 + f * 16 + l16) * 32 + quad * 8);
    #pragma unroll
    for (int fm = 0; fm < 4; ++fm)
      #pragma unroll
      for (int fn = 0; fn < 2; ++fn)
        acc[fm][fn] = mfma_bf16(a[fm], b2[fn], acc[fm][fn]);
    __syncthreads();
  }

  float bv[2];
  #pragma unroll
  for (int fn = 0; fn < 2; ++fn) bv[fn] = bias[n0 + wave * 32 + fn * 16 + l16];

  #pragma unroll
  for (int fm = 0; fm < 4; ++fm)
    #pragma unroll
    for (int r = 0; r < 4; ++r) {
      const int gm = m0 + fm * 16 + quad * 4 + r;
      #pragma unroll
      for (int fn = 0; fn < 2; ++fn) {
        const int gn = n0 + wave * 32 + fn * 16 + l16;
        out[(size_t)gm * EE + gn] = acc[fm][fn][r] + bv[fn];
      }
    }
}

// ---------------- flash attention fwd: O (normalized) + linv -------------
// 256 thr = 4 waves: pair p=w>>1 handles s-half p*1024..+1024 (16 iters of
// 64); tw=w&1 is the t-half (64 t-rows) of the 128-t block tile.
// S^T = K.Q (swapped operands) -> P stays in REGISTERS: two adjacent 16-row
// S^T frags pack into one x32 B-operand (k-permutation matched by gathering
// V^T with two b64 reads). LDS carries only K (b128) + V^T (b64):
// 16KB/wave-iter for 1.05 MFLOP. Q: register-resident from global (scaled
// 1/8 in the Q GEMM). s-halves merged in-block via LDS at epilogue.
// XCD-swizzled flat grid: 16 t-blocks of one (b,h) share an XCD's L2.
__global__ __launch_bounds__(256, 2) void attn_fwd(const __bf16* __restrict__ qb,
                                                   const __bf16* __restrict__ kb,
                                                   const __bf16* __restrict__ vtb,
                                                   __bf16* __restrict__ ob,
                                                   float* __restrict__ linv_ws) {
  union Sh {
    __bf16 kv[2][2][2][64 * 64];  // [pair][K=0/V=1][buf] 64KB
    float om[2][64 * 64];         // epilogue O-merge scratch (32KB, aliased)
  };
  __shared__ Sh sm;
  __shared__ float Lsum[2][128];
  __shared__ float LinvS[128];

  const int tid = threadIdx.x, lane = tid & 63, w = tid >> 6;
  const int p = w >> 1, tw = w & 1;
  const int quad = lane >> 4, l16 = lane & 15;

  // XCD swizzle: bx%8 = XCD (dispatch heuristic); 4 (b,h) groups per XCD,
  // 16 t-tiles per group -> K/V of one (b,h) stays in one XCD's L2.
  const int bx = blockIdx.x;
  const int xcd = bx & 7, slot = bx >> 3;
  const int bhi = xcd * 4 + (slot >> 4);
  const int t0 = (slot & 15) * 128;
  const int b = bhi >> 4, h = bhi & 15;
  const size_t bh = (size_t)(b * HN + h);

  const __bf16* qbase = qb + (bh * TT + t0) * HD;
  const __bf16* kbase = kb + bh * TT * HD;
  const __bf16* vbase = vtb + bh * HD * TT;
  const int sBase = p * 1024;

  // initial stage of buf0 (each wave stages its pair's half-tiles)
  #pragma unroll
  for (int c = 0; c < 4; ++c) {
    stage8(kbase + (size_t)sBase * HD, HD, sm.kv[p][0][0], tw * 32 + c * 8, lane);
    stage8(vbase + sBase, TT, sm.kv[p][1][0], tw * 32 + c * 8, lane);
  }

  // Q frags (B-operand: lane l16 = t, k = e): loop-invariant registers
  bfrag qf[4][2];
  #pragma unroll
  for (int fn = 0; fn < 4; ++fn)
    #pragma unroll
    for (int ks = 0; ks < 2; ++ks)
      qf[fn][ks] = *(const bfrag*)(qbase +
          (size_t)(tw * 64 + fn * 16 + l16) * HD + ks * 32 + quad * 8);

  f32x4 oacc[4][4] = {};   // [fm_d][fn_t] of O^T
  float lpart[4] = {};     // per fn_t, t = tw*64+fn*16+l16

  for (int it = 0; it < 16; ++it) {
    const int cur = it & 1;
    __syncthreads();
    if (it + 1 < 16) {
      const int s1 = sBase + (it + 1) * 64;
      #pragma unroll
      for (int c = 0; c < 4; ++c) {
        stage8(kbase + (size_t)s1 * HD, HD, sm.kv[p][0][1 - cur], tw * 32 + c * 8, lane);
        stage8(vbase + s1, TT, sm.kv[p][1][1 - cur], tw * 32 + c * 8, lane);
      }
    }

    // ---- S^T[s][t] = K.Q (already includes the 1/8 scale via Q)
    f32x4 sacc[4][4] = {};   // [fm_s][fn_t]
    #pragma unroll
    for (int ks = 0; ks < 2; ++ks) {
      bfrag kf[4];
      #pragma unroll
      for (int fm = 0; fm < 4; ++fm)
        kf[fm] = *fragp(sm.kv[p][0][cur], fm * 16 + l16, ks * 32 + quad * 8);
      #pragma unroll
      for (int fm = 0; fm < 4; ++fm)
        #pragma unroll
        for (int fn = 0; fn < 4; ++fn)
          sacc[fm][fn] = mfma_bf16(kf[fm], qf[fn][ks], sacc[fm][fn]);
    }

    // ---- exp in registers; pack pairs of 16-s frags into x32 B-operands
    union PB { __bf16 hh[8]; bfrag v; } pb[2][4];
    #pragma unroll
    for (int fm = 0; fm < 4; ++fm)
      #pragma unroll
      for (int fn = 0; fn < 4; ++fn) {
        const float p0 = __expf(sacc[fm][fn][0]);
        const float p1 = __expf(sacc[fm][fn][1]);
        const float p2 = __expf(sacc[fm][fn][2]);
        const float p3 = __expf(sacc[fm][fn][3]);
        lpart[fn] += (p0 + p1) + (p2 + p3);
        const int hb = (fm & 1) * 4;
        pb[fm >> 1][fn].hh[hb + 0] = (__bf16)p0;
        pb[fm >> 1][fn].hh[hb + 1] = (__bf16)p1;
        pb[fm >> 1][fn].hh[hb + 2] = (__bf16)p2;
        pb[fm >> 1][fn].hh[hb + 3] = (__bf16)p3;
      }

    // ---- O^T[d][t] += V^T.P^T : A = V^T gathered with matching k-perm
    #pragma unroll
    for (int ks = 0; ks < 2; ++ks) {
      bfrag vf[4];
      #pragma unroll
      for (int fm = 0; fm < 4; ++fm) {
        const __bf16* base = sm.kv[p][1][cur] + (fm * 16 + l16) * 64;
        const int sw = l16 & 7, qh = quad >> 1, qo = (quad & 1) * 4;
        union VF { s16x4 q[2]; bfrag v; } u;
        u.q[0] = *(const s16x4*)(base + (((ks * 4 + qh) ^ sw) << 3) + qo);
        u.q[1] = *(const s16x4*)(base + (((ks * 4 + 2 + qh) ^ sw) << 3) + qo);
        vf[fm] = u.v;
      }
      #pragma unroll
      for (int fm = 0; fm < 4; ++fm)
        #pragma unroll
        for (int fn = 0; fn < 4; ++fn)
          oacc[fm][fn] = mfma_bf16(vf[fm], pb[ks][fn].v, oacc[fm][fn]);
    }
  }

  // ---- l partials: butterfly over quads (disjoint s per quad)
  #pragma unroll
  for (int fn = 0; fn < 4; ++fn) {
    float v = lpart[fn];
    v += __shfl_xor(v, 16);
    v += __shfl_xor(v, 32);
    lpart[fn] = v;
  }
  if (quad == 0)
    #pragma unroll
    for (int fn = 0; fn < 4; ++fn)
      Lsum[p][tw * 64 + fn * 16 + l16] = lpart[fn];

  __syncthreads();   // Lsum visible; all K/V reads done -> om may alias

  if (p == 1) {
    #pragma unroll
    for (int fm = 0; fm < 4; ++fm)
      #pragma unroll
      for (int fn = 0; fn < 4; ++fn)
        #pragma unroll
        for (int r = 0; r < 4; ++r)
          sm.om[tw][(fm * 16 + quad * 4 + r) * 64 + fn * 16 + l16] = oacc[fm][fn][r];
  }
  if (tid < 128) {
    const float linv = 1.0f / (Lsum[0][tid] + Lsum[1][tid]);
    LinvS[tid] = linv;
    linv_ws[bh * TT + t0 + tid] = linv;
  }
  __syncthreads();

  if (p == 0) {
    float li[4];
    #pragma unroll
    for (int fn = 0; fn < 4; ++fn) li[fn] = LinvS[tw * 64 + fn * 16 + l16];
    #pragma unroll
    for (int fm = 0; fm < 4; ++fm)
      #pragma unroll
      for (int fn = 0; fn < 4; ++fn) {
        const int t = t0 + tw * 64 + fn * 16 + l16;
        struct alignas(8) B4 { __bf16 a0, a1, a2, a3; };
        B4 o;
        __bf16* op = &o.a0;
        #pragma unroll
        for (int r = 0; r < 4; ++r) {
          const float v = (oacc[fm][fn][r] +
              sm.om[tw][(fm * 16 + quad * 4 + r) * 64 + fn * 16 + l16]) * li[fn];
          op[r] = (__bf16)v;
        }
        *(B4*)(ob + ((size_t)t * BBATCH + b) * EE + h * HD + fm * 16 + quad * 4) = o;
      }
  }
}

// ---------------- avg_w: mean over heads of softmax probs ----------------
// Zero LDS, zero barriers. 4 waves 2x2: block tile 128t x 128s; per head
// load Q/K frags straight from global (16B-contiguous rows, L2-hot).
// Q pre-scaled by 1/8 in the GEMM. 512 blocks, XCD-swizzled by (b,t).
__global__ __launch_bounds__(256, 2) void avg_attn(const __bf16* __restrict__ qb,
                                                   const __bf16* __restrict__ kb,
                                                   const float* __restrict__ linv_ws,
                                                   float* __restrict__ avg_out) {
  const int tid = threadIdx.x, lane = tid & 63, w = tid >> 6;
  const int wm = w >> 1, wn = w & 1;
  const int quad = lane >> 4, l16 = lane & 15;

  const int bx = blockIdx.x;
  const int xcd = bx & 7, slot = bx >> 3;
  const int bti = xcd * 4 + (slot >> 4);
  const int s0 = (slot & 15) * 128;
  const int b = bti >> 4, t0 = (bti & 15) * 128;

  f32x4 aacc[4][4] = {};

  for (int h = 0; h < HN; ++h) {
    const size_t bh = (size_t)(b * HN + h);
    const __bf16* qrow = qb + (bh * TT + t0 + wm * 64) * HD;
    const __bf16* krow = kb + (bh * TT + s0 + wn * 64) * HD;

    bfrag qf4[4][2], kf4[4][2];
    #pragma unroll
    for (int f = 0; f < 4; ++f)
      #pragma unroll
      for (int ks = 0; ks < 2; ++ks) {
        qf4[f][ks] = *(const bfrag*)(qrow + (size_t)(f * 16 + l16) * HD + ks * 32 + quad * 8);
        kf4[f][ks] = *(const bfrag*)(krow + (size_t)(f * 16 + l16) * HD + ks * 32 + quad * 8);
      }

    f32x4 sacc[4][4] = {};
    #pragma unroll
    for (int ks = 0; ks < 2; ++ks)
      #pragma unroll
      for (int fm = 0; fm < 4; ++fm)
        #pragma unroll
        for (int fn = 0; fn < 4; ++fn)
          sacc[fm][fn] = mfma_bf16(qf4[fm][ks], kf4[fn][ks], sacc[fm][fn]);

    f32x4 lvv[4];
    #pragma unroll
    for (int fm = 0; fm < 4; ++fm)
      lvv[fm] = *(const f32x4*)&linv_ws[bh * TT + t0 + wm * 64 + fm * 16 + quad * 4];

    #pragma unroll
    for (int fm = 0; fm < 4; ++fm)
      #pragma unroll
      for (int fn = 0; fn < 4; ++fn)
        #pragma unroll
        for (int r = 0; r < 4; ++r)
          aacc[fm][fn][r] += __expf(sacc[fm][fn][r]) * lvv[fm][r];
  }

  const float invh = 1.0f / (float)HN;
  #pragma unroll
  for (int fm = 0; fm < 4; ++fm)
    #pragma unroll
    for (int r = 0; r < 4; ++r) {
      const int t = t0 + wm * 64 + fm * 16 + quad * 4 + r;
      #pragma unroll
      for (int fn = 0; fn < 4; ++fn) {
        const int s = s0 + wn * 64 + fn * 16 + l16;
        avg_out[((size_t)b * TT + t) * TT + s] = aacc[fm][fn][r] * invh;
      }
    }
}

extern "C" void kernel_launch(void* const* d_in, const int* in_sizes, int n_in,
                              void* d_out, int out_size, void* d_ws, size_t ws_size,
                              hipStream_t stream) {
  (void)in_sizes; (void)n_in; (void)out_size; (void)ws_size;
  const float* query = (const float*)d_in[0];
  const float* key   = (const float*)d_in[1];
  const float* value = (const float*)d_in[2];
  const float* Wq = (const float*)d_in[3];
  const float* bq = (const float*)d_in[4];
  const float* Wk = (const float*)d_in[5];
  const float* bk = (const float*)d_in[6];
  const float* Wv = (const float*)d_in[7];
  const float* bv = (const float*)d_in[8];
  const float* Wo = (const float*)d_in[9];
  const float* bo = (const float*)d_in[10];

  char* ws = (char*)d_ws;
  size_t off = 0;
  auto wsalloc = [&](size_t bytes) -> void* {
    void* p = ws + off;
    off += (bytes + 255) & ~(size_t)255;
    return p;
  };
  const size_t XE = (size_t)MM * EE;
  const size_t WE = (size_t)EE * EE;
  __bf16* xq   = (__bf16*)wsalloc(XE * 2);
  __bf16* xk   = (__bf16*)wsalloc(XE * 2);
  __bf16* xv   = (__bf16*)wsalloc(XE * 2);
  __bf16* wqb  = (__bf16*)wsalloc(WE * 2);
  __bf16* wkb  = (__bf16*)wsalloc(WE * 2);
  __bf16* wvb  = (__bf16*)wsalloc(WE * 2);
  __bf16* wob  = (__bf16*)wsalloc(WE * 2);
  __bf16* qbuf = (__bf16*)wsalloc(XE * 2);
  __bf16* kbuf = (__bf16*)wsalloc(XE * 2);
  __bf16* vtbuf= (__bf16*)wsalloc(XE * 2);
  __bf16* obuf = (__bf16*)wsalloc(XE * 2);
  float* linv  = (float*)wsalloc((size_t)BBATCH * HN * TT * 4);

  CvtArgs ca;
  ca.src[0] = query; ca.dst[0] = xq;  ca.n4[0] = (int)(XE / 4);
  ca.src[1] = key;   ca.dst[1] = xk;  ca.n4[1] = (int)(XE / 4);
  ca.src[2] = value; ca.dst[2] = xv;  ca.n4[2] = (int)(XE / 4);
  ca.src[3] = Wq;    ca.dst[3] = wqb; ca.n4[3] = (int)(WE / 4);
  ca.src[4] = Wk;    ca.dst[4] = wkb; ca.n4[4] = (int)(WE / 4);
  ca.src[5] = Wv;    ca.dst[5] = wvb; ca.n4[5] = (int)(WE / 4);
  ca.src[6] = Wo;    ca.dst[6] = wob; ca.n4[6] = (int)(WE / 4);
  cvt_all<<<dim3(4096, 1, 7), 256, 0, stream>>>(ca);

  gemm_qkv<<<dim3(8, 32, 3), 256, 0, stream>>>(xq, xk, xv, wqb, wkb, wvb,
                                               bq, bk, bv, qbuf, kbuf, vtbuf);

  attn_fwd<<<dim3(512), 256, 0, stream>>>(qbuf, kbuf, vtbuf, obuf, linv);

  float* avg_out = (float*)d_out + (size_t)TT * BBATCH * EE;
  avg_attn<<<dim3(512), 256, 0, stream>>>(qbuf, kbuf, linv, avg_out);

  gemm_o64<<<dim3(8, 64), 256, 0, stream>>>(obuf, wob, bo, (float*)d_out);
}